// Round 3
// baseline (4540.870 us; speedup 1.0000x reference)
//
#include <hip/hip_runtime.h>

#define TT 512
#define II 128
#define HH 1024
#define BB 64

typedef __attribute__((ext_vector_type(8))) short bf16x8;
typedef __attribute__((ext_vector_type(4))) float f32x4;

__device__ __forceinline__ unsigned short f2bf(float f) {
  unsigned u = __builtin_bit_cast(unsigned, f);
  u += 0x7fffu + ((u >> 16) & 1u);   // round-to-nearest-even
  return (unsigned short)(u >> 16);
}

__device__ __forceinline__ bf16x8 load8f_bf(const float* p) {
  const f32x4* q = (const f32x4*)p;
  f32x4 a = q[0];
  f32x4 b = q[1];
  bf16x8 r;
  r[0] = (short)f2bf(a[0]); r[1] = (short)f2bf(a[1]);
  r[2] = (short)f2bf(a[2]); r[3] = (short)f2bf(a[3]);
  r[4] = (short)f2bf(b[0]); r[5] = (short)f2bf(b[1]);
  r[6] = (short)f2bf(b[2]); r[7] = (short)f2bf(b[3]);
  return r;
}

__device__ __forceinline__ float sigm(float v) { return 1.f / (1.f + __expf(-v)); }
__device__ __forceinline__ float tanh_f(float v) { return 2.f / (1.f + __expf(-2.f * v)) - 1.f; }

// Coherent h-tile load: relaxed agent-scope atomic loads lower to
// global_load_dwordx2 with the right sc bits for gfx950 (bypass L1/L2, read
// at the LLC coherence point). This replaces the round-0/1 scheme of plain
// cached loads + per-step agent-acquire fence: the fence's buffer_inv nuked
// the ENTIRE L2 every step, evicting weights/x and turning the (measured,
// VGPR_Count=128) weight-remat re-reads into LLC traffic — the dominant
// per-step cost. With sc-coherent h loads, no fence is needed at all and L2
// stays warm for weights/x across all 512 steps.
__device__ __forceinline__ bf16x8 ld_h8(const unsigned short* p) {
  unsigned long long lo = __hip_atomic_load((unsigned long long*)p,
      __ATOMIC_RELAXED, __HIP_MEMORY_SCOPE_AGENT);
  unsigned long long hi = __hip_atomic_load((unsigned long long*)(p + 4),
      __ATOMIC_RELAXED, __HIP_MEMORY_SCOPE_AGENT);
  union { unsigned long long q[2]; bf16x8 v; } u;
  u.q[0] = lo; u.q[1] = hi;
  return u.v;
}

// Monotonic 8-way-split group barrier: 64 WGs per group, 8 arrive-counters
// per group (rank%8 -> counter, 64B apart => 8-way instead of 64-way
// same-address RMW serialization at the LLC). Counters are monotone: each
// counter gains +8 per step; target for barrier #b is 8*b. No reset, no
// winner branch, no publish hop, and NO FENCES:
//  - producer: h stores are sc-coherent (complete at LLC); __syncthreads'
//    workgroup fence drains vmcnt(0) per wave BEFORE wave 0 issues the
//    arrive RMW, so an observed increment implies that WG's h is at LLC.
//  - consumer: wave 0 lanes 0-7 poll the 8 counters in parallel (relaxed
//    agent atomic loads, sc-coherent); h loads after the barrier are
//    themselves sc-coherent, so no cache invalidate is required.
__device__ __forceinline__ void group_barrier(int* bar, int g, int rank, int tgt8) {
  __syncthreads();
  if (threadIdx.x < 64) {
    const int lane = threadIdx.x;
    if (lane == (rank & 7)) {
      __hip_atomic_fetch_add(bar + (g * 8 + lane) * 16, 1,
          __ATOMIC_RELAXED, __HIP_MEMORY_SCOPE_AGENT);
    }
    bool ok;
    do {
      int v = tgt8;
      if (lane < 8)
        v = __hip_atomic_load(bar + (g * 8 + lane) * 16,
            __ATOMIC_RELAXED, __HIP_MEMORY_SCOPE_AGENT);
      ok = __all(v >= tgt8);
      if (!ok) __builtin_amdgcn_s_sleep(1);
    } while (!ok);
  }
  __syncthreads();
}

// 256 WGs x 512 threads (8 waves), 1 WG/CU. 4 groups x 64 WGs; group g owns
// batches [16g,16g+16). WG owns 16 hidden units per layer.
// Waves 0-3: layer0 (K=1152, 4-way split, 9 kt each, weights in VGPRs).
// Waves 4-7: layer1 (K=2048, 4-way split, 16 kt: 9 in VGPRs + 7 in LDS).
//
// Register budget: rounds 0-1 measured VGPR_Count=128 + FETCH_SIZE 635 MB —
// the 144-VGPR weight array was NOT resident (rematerialized as in-loop
// global re-reads) despite launch_bounds(512)+waves_per_eu(2,2). This round:
// no __launch_bounds__, exact amdgpu_flat_work_group_size(512,512) +
// waves_per_eu(2,2) so the backend sees exactly 8 waves/WG and a hard
// 2-waves/EU target (=> 256-VGPR allocator budget). VERIFY: VGPR_Count
// must move off 128; if it doesn't, next lever is amdgpu_num_vgpr(256) or
// prepacked-bf16 weights in workspace to cheapen the remat.
__global__ __attribute__((amdgpu_flat_work_group_size(512, 512), amdgpu_waves_per_eu(2, 2)))
void lstm_persistent(
    const float* __restrict__ x, const float* __restrict__ h0,
    const float* __restrict__ c0,
    const float* __restrict__ Wih0, const float* __restrict__ Whh0,
    const float* __restrict__ bih0, const float* __restrict__ bhh0,
    const float* __restrict__ Wih1, const float* __restrict__ Whh1,
    const float* __restrict__ bih1, const float* __restrict__ bhh1,
    const float* __restrict__ Wfc, const float* __restrict__ bfc,
    float* __restrict__ out, unsigned short* __restrict__ hbuf, int* __restrict__ bar)
{
  const int tid  = threadIdx.x;
  const int lane = tid & 63;
  const int wv   = tid >> 6;         // 0..7
  const int L    = wv >> 2;          // 0: layer0 waves, 1: layer1 waves
  const int kwv  = wv & 3;           // K-split index within layer
  const int bid  = blockIdx.x;
  const int g    = bid >> 6;
  const int rank = bid & 63;
  const int gbase = g * 16;
  const int ubase = rank * 16;

  unsigned short* h1s = hbuf;                  // [2][64][1024] bf16 double-buffered (layer0 h)
  unsigned short* h2s = hbuf + 2 * BB * HH;    // layer1 h

  __shared__ float lds_part[2][4][64][17];     // [layer][kwv][gate-row][batch pad17]
  __shared__ float lds_bias[128];
  __shared__ float lds_out[16];
  extern __shared__ __align__(16) unsigned short lds_w[];  // 4*7*4*64 frags * 16B = 114688B

  const int n  = lane & 15;
  const int ko = (lane >> 4) * 8;

  // ---- pack weights: registers (both layers) + LDS (layer1 kt 9..15) ----
  bf16x8 w[4][9];
  if (L == 0) {
#pragma unroll
    for (int nt = 0; nt < 4; ++nt) {
      int r = nt * 16 + n;                       // local row: unit=r>>2, gate=r&3
      int R = (r & 3) * HH + ubase + (r >> 2);   // gate*H + unit (i,f,g,o)
#pragma unroll
      for (int kt = 0; kt < 9; ++kt) {
        int c = kwv * 288 + kt * 32 + ko;        // col in [0,1152)
        const float* src = (c < II) ? (Wih0 + (size_t)R * II + c)
                                    : (Whh0 + (size_t)R * HH + (c - II));
        w[nt][kt] = load8f_bf(src);
      }
    }
  } else {
#pragma unroll
    for (int nt = 0; nt < 4; ++nt) {
      int r = nt * 16 + n;
      int R = (r & 3) * HH + ubase + (r >> 2);
#pragma unroll
      for (int kt = 0; kt < 16; ++kt) {
        int c = kwv * 512 + kt * 32 + ko;        // col in [0,2048)
        const float* src = (c < HH) ? (Wih1 + (size_t)R * HH + c)
                                    : (Whh1 + (size_t)R * HH + (c - HH));
        bf16x8 f = load8f_bf(src);
        if (kt < 9) {
          w[nt][kt] = f;
        } else {
          int fi = ((kwv * 7 + (kt - 9)) * 4 + nt) * 64 + lane;
          ((bf16x8*)lds_w)[fi] = f;
        }
      }
    }
  }

  // combined biases -> LDS
  if (tid < 128) {
    int Lr = tid >> 6, r = tid & 63;
    int R = (r & 3) * HH + ubase + (r >> 2);
    lds_bias[tid] = (Lr == 0) ? (bih0[R] + bhh0[R]) : (bih1[R] + bhh1[R]);
  }

  // epilogue mapping: 512 threads = 2 layers x 16 units x 16 batches
  const int eL = tid >> 8;
  const int eu = tid & 15;
  const int em = (tid >> 4) & 15;
  const int b_e = gbase + em;
  const int u_e = ubase + eu;
  float c_st = c0[eL * BB * HH + b_e * HH + u_e];
  const float wfc_r = Wfc[u_e];

  // init h double-buffers: slot 1 <- h0 (coherent 4B stores: read cross-XCD at p=0/1)
  if (rank < 16) {
    int b = gbase + rank;
    int u = tid * 2;  // 512 threads x 2 units = 1024 = HH exactly
    unsigned p1 = (unsigned)f2bf(h0[0 * BB * HH + b * HH + u]) |
                  ((unsigned)f2bf(h0[0 * BB * HH + b * HH + u + 1]) << 16);
    unsigned p2 = (unsigned)f2bf(h0[1 * BB * HH + b * HH + u]) |
                  ((unsigned)f2bf(h0[1 * BB * HH + b * HH + u + 1]) << 16);
    __hip_atomic_store((unsigned*)(h1s + BB * HH + b * HH + u), p1,
        __ATOMIC_RELAXED, __HIP_MEMORY_SCOPE_AGENT);
    __hip_atomic_store((unsigned*)(h2s + BB * HH + b * HH + u), p2,
        __ATOMIC_RELAXED, __HIP_MEMORY_SCOPE_AGENT);
  }
  // init out with b_fc at the LLC (atomics accumulate onto it there)
  if (rank == 0) {
    float bf = bfc[0];
    for (int i = tid; i < 16 * TT; i += 512)
      __hip_atomic_store(&out[(gbase + (i >> 9)) * TT + (i & 511)], bf,
          __ATOMIC_RELAXED, __HIP_MEMORY_SCOPE_AGENT);
  }

  group_barrier(bar, g, rank, 8);   // barrier #1

  const int bA = gbase + n;   // A-fragment batch (m = lane&15)

  for (int p = 0; p <= TT; ++p) {
    const bool l0act = (p < TT);
    const bool l1act = (p >= 1);
    const unsigned short* h1r = h1s + ((p - 1) & 1) * (BB * HH);  // h1[p-1]
    const unsigned short* h2r = h2s + (p & 1) * (BB * HH);        // h2[p-2]

    f32x4 acc[4];
#pragma unroll
    for (int nt = 0; nt < 4; ++nt) acc[nt] = (f32x4){0.f, 0.f, 0.f, 0.f};

    if (L == 0) {
      if (l0act) {
        if (kwv == 0) {
#pragma unroll
          for (int kt = 0; kt < 4; ++kt) {             // cols 0..127: from x (fp32, L2-cached)
            bf16x8 a = load8f_bf(x + ((size_t)bA * TT + p) * II + kt * 32 + ko);
#pragma unroll
            for (int nt = 0; nt < 4; ++nt)
              acc[nt] = __builtin_amdgcn_mfma_f32_16x16x32_bf16(a, w[nt][kt], acc[nt], 0, 0, 0);
          }
#pragma unroll
          for (int kt = 4; kt < 9; ++kt) {             // cols 128..287: h1[p-1] (LLC)
            bf16x8 a = ld_h8(h1r + (size_t)bA * HH + (kt * 32 + ko - II));
#pragma unroll
            for (int nt = 0; nt < 4; ++nt)
              acc[nt] = __builtin_amdgcn_mfma_f32_16x16x32_bf16(a, w[nt][kt], acc[nt], 0, 0, 0);
          }
        } else {
#pragma unroll
          for (int kt = 0; kt < 9; ++kt) {             // all from h1[p-1]
            int off = kwv * 288 + kt * 32 + ko - II;
            bf16x8 a = ld_h8(h1r + (size_t)bA * HH + off);
#pragma unroll
            for (int nt = 0; nt < 4; ++nt)
              acc[nt] = __builtin_amdgcn_mfma_f32_16x16x32_bf16(a, w[nt][kt], acc[nt], 0, 0, 0);
          }
        }
      }
    } else {
      if (l1act) {
        // kwv 0,1 read h1[p-1]; kwv 2,3 read h2[p-2]
        const unsigned short* hb = (kwv < 2) ? h1r : h2r;
        const int kbase = (kwv & 1) * 512;
#pragma unroll
        for (int kt = 0; kt < 9; ++kt) {
          bf16x8 a = ld_h8(hb + (size_t)bA * HH + kbase + kt * 32 + ko);
#pragma unroll
          for (int nt = 0; nt < 4; ++nt)
            acc[nt] = __builtin_amdgcn_mfma_f32_16x16x32_bf16(a, w[nt][kt], acc[nt], 0, 0, 0);
        }
#pragma unroll
        for (int kt = 9; kt < 16; ++kt) {
          bf16x8 a = ld_h8(hb + (size_t)bA * HH + kbase + kt * 32 + ko);
#pragma unroll
          for (int nt = 0; nt < 4; ++nt) {
            bf16x8 wf = ((const bf16x8*)lds_w)[((kwv * 7 + (kt - 9)) * 4 + nt) * 64 + lane];
            acc[nt] = __builtin_amdgcn_mfma_f32_16x16x32_bf16(a, wf, acc[nt], 0, 0, 0);
          }
        }
      }
    }

    // stage partials to LDS (D layout: n-row = lane&15, m = (lane>>4)*4 + reg)
    {
      const bool act = (L == 0) ? l0act : l1act;
      if (act) {
        const int m0 = (lane >> 4) * 4;
#pragma unroll
        for (int nt = 0; nt < 4; ++nt) {
          int row = nt * 16 + n;
#pragma unroll
          for (int r = 0; r < 4; ++r)
            lds_part[L][kwv][row][m0 + r] = acc[nt][r];
        }
      }
    }
    if (tid < 16) lds_out[tid] = 0.f;
    __syncthreads();

    // epilogue: 1 (layer,unit,batch) per thread; c-state in register
    const bool eact = (eL == 0) ? l0act : l1act;
    if (eact) {
      float pre[4];
#pragma unroll
      for (int q = 0; q < 4; ++q) {
        float s = lds_bias[eL * 64 + eu * 4 + q];
#pragma unroll
        for (int w2 = 0; w2 < 4; ++w2)
          s += lds_part[eL][w2][eu * 4 + q][em];
        pre[q] = s;
      }
      float iv = sigm(pre[0]);
      float fv = sigm(pre[1]);
      float gv = tanh_f(pre[2]);
      float ov = sigm(pre[3]);
      c_st = fv * c_st + iv * gv;
      float hv = ov * tanh_f(c_st);
      // pack 2 adjacent units (even/odd eu = adjacent lanes) into one 4B
      // coherent store: avoids 16-bit atomic stores and halves store count.
      unsigned short hb16 = f2bf(hv);
      int partner = __shfl_xor((int)hb16, 1);
      unsigned short* hdst = (eL == 0) ? (h1s + (p & 1) * (BB * HH))          // h1[p]
                                       : (h2s + ((p - 1) & 1) * (BB * HH));   // h2[p-1]
      if ((lane & 1) == 0) {
        unsigned pk = (unsigned)hb16 | ((unsigned)partner << 16);
        __hip_atomic_store((unsigned*)(hdst + b_e * HH + u_e), pk,
            __ATOMIC_RELAXED, __HIP_MEMORY_SCOPE_AGENT);
      }
      if (eL == 1) atomicAdd(&lds_out[em], hv * wfc_r);                       // FC partial
    }
    __syncthreads();   // lds_out complete; per-wave vmcnt drain covers h stores
    if (l1act && tid < 16)
      atomicAdd(&out[(gbase + tid) * TT + (p - 1)], lds_out[tid]);  // fire-and-forget

    if (p < TT) group_barrier(bar, g, rank, 8 * (p + 2));   // barrier #(p+2)
  }
}

extern "C" void kernel_launch(void* const* d_in, const int* in_sizes, int n_in,
                              void* d_out, int out_size, void* d_ws, size_t ws_size,
                              hipStream_t stream) {
  (void)in_sizes; (void)n_in; (void)out_size; (void)ws_size;
  hipMemsetAsync(d_ws, 0, 4096, stream);   // 4 groups x 8 counters x 64B = 2KB of barrier state
  int* bar = (int*)d_ws;
  unsigned short* hbuf = (unsigned short*)((char*)d_ws + 4096);  // 512 KB h buffers
  hipLaunchKernelGGL(lstm_persistent, dim3(256), dim3(512), 114688, stream,
      (const float*)d_in[0], (const float*)d_in[1], (const float*)d_in[2],
      (const float*)d_in[3], (const float*)d_in[4], (const float*)d_in[5],
      (const float*)d_in[6], (const float*)d_in[7], (const float*)d_in[8],
      (const float*)d_in[9], (const float*)d_in[10], (const float*)d_in[11],
      (const float*)d_in[12], (float*)d_out, hbuf, bar);
}